// Round 1
// baseline (1514.550 us; speedup 1.0000x reference)
//
#include <hip/hip_runtime.h>
#include <math.h>

#define NN      50000
#define E_CNT   800000
#define IN_C    512
#define HID     128
#define OUT_C   40
#define NHEAD   8
#define CPH     16
#define NLAYER  5
#define NEG     0.2f
#define CAP     512   // staged-in-LDS edge cap per node; fallback to global beyond

__device__ __forceinline__ float lrelu(float x) { return x > 0.f ? x : NEG * x; }
__device__ __forceinline__ float eluf(float x)  { return x > 0.f ? x : expm1f(x); }

// ---------------- GEMM: [NN,K] @ [K,128] (+bias) -> [NN,128] -----------------
// Block = 256 threads computes a 32x128 tile. thread: col c = tid&127, row-half g.
template<int K, bool BIAS>
__global__ __launch_bounds__(256) void k_gemm128(const float* __restrict__ a,
                                                 const float* __restrict__ w,
                                                 const float* __restrict__ bias,
                                                 float* __restrict__ out) {
    __shared__ float xs[32][33];
    const int tid  = threadIdx.x;
    const int c    = tid & 127;
    const int g    = tid >> 7;
    const int row0 = blockIdx.x * 32;
    float acc[16];
#pragma unroll
    for (int r = 0; r < 16; ++r) acc[r] = 0.f;

    for (int k0 = 0; k0 < K; k0 += 32) {
#pragma unroll
        for (int idx = tid; idx < 1024; idx += 256) {
            int r = idx >> 5, k = idx & 31;
            int row = row0 + r;
            xs[r][k] = (row < NN) ? a[row * K + k0 + k] : 0.f;
        }
        __syncthreads();
#pragma unroll 4
        for (int k = 0; k < 32; ++k) {
            float wv = w[(k0 + k) * HID + c];
#pragma unroll
            for (int r = 0; r < 16; ++r) acc[r] += xs[g * 16 + r][k] * wv;
        }
        __syncthreads();
    }
    float bv = BIAS ? bias[c] : 0.f;
#pragma unroll
    for (int r = 0; r < 16; ++r) {
        int row = row0 + g * 16 + r;
        if (row < NN) out[row * HID + c] = acc[r] + bv;
    }
}

// ---------------- attention coefficients: a_src/a_dst [NN,8] -----------------
__global__ void k_att(const float* __restrict__ hp,
                      const float* __restrict__ attS, const float* __restrict__ attD,
                      float* __restrict__ aS, float* __restrict__ aD) {
    int i = blockIdx.x * blockDim.x + threadIdx.x;   // n*8 + h
    if (i >= NN * NHEAD) return;
    int h = i & 7;
    const float* row = hp + (i >> 3) * HID + h * CPH;
    float s = 0.f, d = 0.f;
#pragma unroll
    for (int c = 0; c < CPH; ++c) {
        float v = row[c];
        s += v * attS[h * CPH + c];
        d += v * attD[h * CPH + c];
    }
    aS[i] = s; aD[i] = d;
}

// ---------------- CSR build ----------------
__global__ void k_hist(const int* __restrict__ dst, int* __restrict__ deg) {
    int e = blockIdx.x * blockDim.x + threadIdx.x;
    if (e < E_CNT) atomicAdd(&deg[dst[e]], 1);
}

__global__ __launch_bounds__(1024) void k_scan(const int* __restrict__ deg,
                                               int* __restrict__ rowstart,
                                               int* __restrict__ cursor) {
    __shared__ int s[1024];
    const int t = threadIdx.x;
    int base = 0;
    const int nchunk = (NN + 1023) / 1024;
    for (int chunk = 0; chunk < nchunk; ++chunk) {
        int i = chunk * 1024 + t;
        int v = (i < NN) ? deg[i] : 0;
        s[t] = v;
        __syncthreads();
        for (int off = 1; off < 1024; off <<= 1) {
            int add = (t >= off) ? s[t - off] : 0;
            __syncthreads();
            s[t] += add;
            __syncthreads();
        }
        int excl = s[t] - v;
        if (i < NN) { rowstart[i] = base + excl; cursor[i] = base + excl; }
        base += s[1023];
        __syncthreads();
    }
    if (t == 0) rowstart[NN] = base;
}

__global__ void k_scatter(const int* __restrict__ src, const int* __restrict__ dst,
                          int* __restrict__ cursor, int* __restrict__ csr) {
    int e = blockIdx.x * blockDim.x + threadIdx.x;
    if (e < E_CNT) {
        int p = atomicAdd(&cursor[dst[e]], 1);
        csr[p] = src[e];
    }
}

// ---------------- layer 0 (gat_conv(0) == conv_bias exactly) ----------------
__global__ void k_layer0(const float* __restrict__ h0, const float* __restrict__ bias,
                         const float* __restrict__ alphas, float* __restrict__ out) {
    int i = blockIdx.x * blockDim.x + threadIdx.x;
    if (i >= NN * HID) return;
    int ch = i & (HID - 1);
    float g = eluf(bias[ch]);
    out[i] = 2.f * g + alphas[NLAYER - 1] * h0[i];
}

// ---------------- GAT aggregation + Clenshaw epilogue (one wave per node) ----
__global__ __launch_bounds__(256) void k_agg(
    const float* __restrict__ hp, const float* __restrict__ aS, const float* __restrict__ aD,
    const int* __restrict__ rowstart, const int* __restrict__ csr,
    const float* __restrict__ bias, const float* __restrict__ h0,
    const float* __restrict__ sl, const float* __restrict__ alphas, int aidx,
    float* __restrict__ hnew) {
    __shared__ int slds[4][CAP];
    const int wave = threadIdx.x >> 6;
    const int lane = threadIdx.x & 63;
    const int n    = blockIdx.x * 4 + wave;      // grid = NN/4 exactly
    const int h    = lane >> 3;                  // 8 lanes per head
    const int rs   = rowstart[n];
    const int deg  = rowstart[n + 1] - rs;
    const int cnt  = deg < CAP ? deg : CAP;

    for (int j = lane; j < cnt; j += 64) slds[wave][j] = csr[rs + j];
    __syncthreads();

    const float adst = aD[n * NHEAD + h];
    const float e0   = lrelu(aS[n * NHEAD + h] + adst);   // self-loop logit

    // pass 1: max
    float m = e0;
    for (int j = 0; j < deg; ++j) {
        int s = (j < CAP) ? slds[wave][j] : csr[rs + j];
        m = fmaxf(m, lrelu(aS[s * NHEAD + h] + adst));
    }
    // pass 2: denom
    float den = expf(e0 - m);
    for (int j = 0; j < deg; ++j) {
        int s = (j < CAP) ? slds[wave][j] : csr[rs + j];
        den += expf(lrelu(aS[s * NHEAD + h] + adst) - m);
    }
    const float inv = 1.f / (den + 1e-16f);

    // pass 3: weighted sum of hp rows (2 channels per lane, coalesced float2)
    const float2* hp2 = (const float2*)hp;
    float2 hvs = hp2[n * 64 + lane];
    float w0   = expf(e0 - m) * inv;
    float accx = hvs.x * w0, accy = hvs.y * w0;
    for (int j = 0; j < deg; ++j) {
        int s = (j < CAP) ? slds[wave][j] : csr[rs + j];
        float wgt = expf(lrelu(aS[s * NHEAD + h] + adst) - m) * inv;
        float2 v = hp2[s * 64 + lane];
        accx += v.x * wgt; accy += v.y * wgt;
    }

    // epilogue: +bias, elu, 2*g - second_last + alpha*h0
    const int ch = lane * 2;
    float g0 = eluf(accx + bias[ch]);
    float g1 = eluf(accy + bias[ch + 1]);
    const float ac = alphas[aidx];
    const float2 s2 = ((const float2*)sl)[n * 64 + lane];
    const float2 hh = ((const float2*)h0)[n * 64 + lane];
    float2 o;
    o.x = 2.f * g0 - s2.x + ac * hh.x;
    o.y = 2.f * g1 - s2.y + ac * hh.y;
    ((float2*)hnew)[n * 64 + lane] = o;
}

// ---------------- final: [NN,128] @ [128,40] + bias, log_softmax -------------
__global__ __launch_bounds__(64) void k_out(const float* __restrict__ t,
                                            const float* __restrict__ w,
                                            const float* __restrict__ b,
                                            float* __restrict__ out) {
    const int n = blockIdx.x;
    const int lane = threadIdx.x;
    float acc = 0.f;
    if (lane < OUT_C) {
        for (int k = 0; k < HID; ++k) acc += t[n * HID + k] * w[k * OUT_C + lane];
        acc += b[lane];
    }
    float v = (lane < OUT_C) ? acc : -INFINITY;
    for (int off = 32; off; off >>= 1) v = fmaxf(v, __shfl_down(v, off));
    float mx = __shfl(v, 0);
    float ex = (lane < OUT_C) ? expf(acc - mx) : 0.f;
    float sv = ex;
    for (int off = 32; off; off >>= 1) sv += __shfl_down(sv, off);
    float lse = logf(__shfl(sv, 0));
    if (lane < OUT_C) out[n * OUT_C + lane] = acc - mx - lse;
}

// ---------------- host ----------------
extern "C" void kernel_launch(void* const* d_in, const int* in_sizes, int n_in,
                              void* d_out, int out_size, void* d_ws, size_t ws_size,
                              hipStream_t stream) {
    const float* x      = (const float*)d_in[0];
    const int*   ei     = (const int*)  d_in[1];
    const float* fc0w   = (const float*)d_in[2];
    const float* fc0b   = (const float*)d_in[3];
    const float* linw   = (const float*)d_in[4];
    const float* attS   = (const float*)d_in[5];
    const float* attD   = (const float*)d_in[6];
    const float* cbias  = (const float*)d_in[7];
    const float* alphas = (const float*)d_in[8];
    const float* fc1w   = (const float*)d_in[9];
    const float* fc1b   = (const float*)d_in[10];
    float* out = (float*)d_out;

    char* p = (char*)d_ws;
    auto alloc = [&](size_t bytes) { void* q = (void*)p; p += (bytes + 255) / 256 * 256; return q; };
    float* h0  = (float*)alloc((size_t)NN * HID * 4);
    float* bA  = (float*)alloc((size_t)NN * HID * 4);
    float* bB  = (float*)alloc((size_t)NN * HID * 4);
    float* bC  = (float*)alloc((size_t)NN * HID * 4);
    float* hp  = (float*)alloc((size_t)NN * HID * 4);
    float* aS  = (float*)alloc((size_t)NN * NHEAD * 4);
    float* aD  = (float*)alloc((size_t)NN * NHEAD * 4);
    int* deg      = (int*)alloc((size_t)(NN + 1) * 4);
    int* rowstart = (int*)alloc((size_t)(NN + 1) * 4);
    int* cursor   = (int*)alloc((size_t)NN * 4);
    int* csr      = (int*)alloc((size_t)E_CNT * 4);

    const int* esrc = ei;
    const int* edst = ei + E_CNT;

    // CSR build (graph identical for all layers)
    hipMemsetAsync(deg, 0, (size_t)NN * 4, stream);
    k_hist<<<(E_CNT + 255) / 256, 256, 0, stream>>>(edst, deg);
    k_scan<<<1, 1024, 0, stream>>>(deg, rowstart, cursor);
    k_scatter<<<(E_CNT + 255) / 256, 256, 0, stream>>>(esrc, edst, cursor, csr);

    // h0 = x @ fc0_w + fc0_b
    k_gemm128<IN_C, true><<<(NN + 31) / 32, 256, 0, stream>>>(x, fc0w, fc0b, h0);

    // second_last = 0 ; layer 0 shortcut
    hipMemsetAsync(bB, 0, (size_t)NN * HID * 4, stream);
    k_layer0<<<(NN * HID + 255) / 256, 256, 0, stream>>>(h0, cbias, alphas, bA);

    float* last = bA; float* sl = bB; float* nxt = bC;
    for (int i = 1; i < NLAYER; ++i) {
        k_gemm128<HID, false><<<(NN + 31) / 32, 256, 0, stream>>>(last, linw + (size_t)i * HID * HID, nullptr, hp);
        k_att<<<(NN * NHEAD + 255) / 256, 256, 0, stream>>>(hp, attS + i * NHEAD * CPH, attD + i * NHEAD * CPH, aS, aD);
        k_agg<<<NN / 4, 256, 0, stream>>>(hp, aS, aD, rowstart, csr,
                                          cbias + i * HID, h0, sl, alphas, NLAYER - 1 - i, nxt);
        float* tmp = sl; sl = last; last = nxt; nxt = tmp;
    }

    k_out<<<NN, 64, 0, stream>>>(last, fc1w, fc1b, out);
}

// Round 2
// 987.775 us; speedup vs baseline: 1.5333x; 1.5333x over previous
//
#include <hip/hip_runtime.h>
#include <math.h>

#define NN      50000
#define E_CNT   800000
#define IN_C    512
#define HID     128
#define OUT_C   40
#define NHEAD   8
#define CPH     16
#define NLAYER  5
#define NEG     0.2f
#define CAP     128   // LDS-staged neighbor cap per node (random graph: deg~Pois(16))

__device__ __forceinline__ float lrelu(float x) { return x > 0.f ? x : NEG * x; }
__device__ __forceinline__ float eluf(float x)  { return x > 0.f ? x : expm1f(x); }

__device__ __forceinline__ float2 bf2f2(unsigned int u) {
    union { unsigned int a; float f; } lo, hi;
    lo.a = u << 16; hi.a = u & 0xffff0000u;
    return make_float2(lo.f, hi.f);
}
__device__ __forceinline__ unsigned short f2bf(float f) {
    union { float f; unsigned int u; } v; v.f = f;
    return (unsigned short)((v.u + 0x7fffu + ((v.u >> 16) & 1u)) >> 16);
}

// ---------- GEMM [NN,K] @ [K,128] : 64x128 tile, 16x2 register tile/thread ----------
// OUT_BF16=0: out_f = a@w + bias (fp32).  OUT_BF16=1: out_b = bf16(a@w), no bias.
template<int K, int OUT_BF16>
__global__ __launch_bounds__(256) void k_gemm128(const float* __restrict__ a,
                                                 const float* __restrict__ w,
                                                 const float* __restrict__ bias,
                                                 float* __restrict__ out_f,
                                                 unsigned short* __restrict__ out_b) {
    __shared__ float xs[64][36];           // 36-word rows: 16B-aligned row base, no conflicts
    const int tid  = threadIdx.x;
    const int c    = tid & 63;             // cols c and c+64
    const int g    = tid >> 6;             // row group (one wave per group)
    const int row0 = blockIdx.x * 64;
    float acc[16][2];
#pragma unroll
    for (int r = 0; r < 16; ++r) { acc[r][0] = 0.f; acc[r][1] = 0.f; }

    for (int k0 = 0; k0 < K; k0 += 32) {
#pragma unroll
        for (int l = 0; l < 2; ++l) {
            int idx = (tid + l * 256) * 4;         // 0..2047 step 4
            int r = idx >> 5, kk = idx & 31;
            int row = row0 + r;
            float4 v = make_float4(0.f, 0.f, 0.f, 0.f);
            if (row < NN) v = *(const float4*)&a[(size_t)row * K + k0 + kk];
            *(float4*)&xs[r][kk] = v;
        }
        __syncthreads();
#pragma unroll
        for (int k4 = 0; k4 < 8; ++k4) {
            float wv0[4], wv1[4];
#pragma unroll
            for (int kk = 0; kk < 4; ++kk) {
                wv0[kk] = w[(size_t)(k0 + k4 * 4 + kk) * HID + c];
                wv1[kk] = w[(size_t)(k0 + k4 * 4 + kk) * HID + c + 64];
            }
#pragma unroll
            for (int r = 0; r < 16; ++r) {
                float4 x4 = *(const float4*)&xs[g * 16 + r][k4 * 4];   // wave-broadcast
                acc[r][0] += x4.x * wv0[0] + x4.y * wv0[1] + x4.z * wv0[2] + x4.w * wv0[3];
                acc[r][1] += x4.x * wv1[0] + x4.y * wv1[1] + x4.z * wv1[2] + x4.w * wv1[3];
            }
        }
        __syncthreads();
    }
#pragma unroll
    for (int r = 0; r < 16; ++r) {
        int row = row0 + g * 16 + r;
        if (row < NN) {
            if (OUT_BF16) {
                out_b[(size_t)row * HID + c]      = f2bf(acc[r][0]);
                out_b[(size_t)row * HID + c + 64] = f2bf(acc[r][1]);
            } else {
                out_f[(size_t)row * HID + c]      = acc[r][0] + bias[c];
                out_f[(size_t)row * HID + c + 64] = acc[r][1] + bias[c + 64];
            }
        }
    }
}

// ---------- attention coefficients from bf16 hp ----------
__global__ void k_att(const unsigned short* __restrict__ hpb,
                      const float* __restrict__ attS, const float* __restrict__ attD,
                      float* __restrict__ aS, float* __restrict__ aD) {
    int i = blockIdx.x * blockDim.x + threadIdx.x;   // n*8 + h
    if (i >= NN * NHEAD) return;
    int h = i & 7;
    const unsigned int* row = (const unsigned int*)(hpb + (size_t)(i >> 3) * HID + h * CPH);
    float s = 0.f, d = 0.f;
#pragma unroll
    for (int cc = 0; cc < 8; ++cc) {
        float2 v = bf2f2(row[cc]);
        s += v.x * attS[h * CPH + 2 * cc] + v.y * attS[h * CPH + 2 * cc + 1];
        d += v.x * attD[h * CPH + 2 * cc] + v.y * attD[h * CPH + 2 * cc + 1];
    }
    aS[i] = s; aD[i] = d;
}

// ---------- CSR build ----------
__global__ void k_hist(const int* __restrict__ dst, int* __restrict__ deg) {
    int e = blockIdx.x * blockDim.x + threadIdx.x;
    if (e < E_CNT) atomicAdd(&deg[dst[e]], 1);
}

__global__ __launch_bounds__(1024) void k_part(const int* __restrict__ deg, int* __restrict__ part) {
    int i = blockIdx.x * 1024 + threadIdx.x;
    int v = (i < NN) ? deg[i] : 0;
    for (int off = 32; off; off >>= 1) v += __shfl_down(v, off);
    __shared__ int ws[16];
    if ((threadIdx.x & 63) == 0) ws[threadIdx.x >> 6] = v;
    __syncthreads();
    if (threadIdx.x < 16) {
        int t = ws[threadIdx.x];
        for (int off = 8; off; off >>= 1) t += __shfl_down(t, off);
        if (threadIdx.x == 0) part[blockIdx.x] = t;
    }
}

__global__ void k_scanpart(int* __restrict__ part, int* __restrict__ rowstart, int nb) {
    int t = threadIdx.x;             // 64 threads, nb<=64
    int v = (t < nb) ? part[t] : 0;
    int x = v;
    for (int off = 1; off < 64; off <<= 1) { int u = __shfl_up(x, off); if (t >= off) x += u; }
    if (t < nb) part[t] = x - v;     // exclusive
    if (t == nb - 1) rowstart[NN] = x;
}

__global__ __launch_bounds__(1024) void k_scanblk(const int* __restrict__ deg,
                                                  const int* __restrict__ partx,
                                                  int* __restrict__ rowstart,
                                                  int* __restrict__ cursor) {
    int b = blockIdx.x, t = threadIdx.x, i = b * 1024 + t;
    int v = (i < NN) ? deg[i] : 0;
    int x = v;
    for (int off = 1; off < 64; off <<= 1) { int u = __shfl_up(x, off); if ((t & 63) >= off) x += u; }
    __shared__ int ws[16];
    if ((t & 63) == 63) ws[t >> 6] = x;
    __syncthreads();
    if (t < 64) {
        int wv = (t < 16) ? ws[t] : 0;
        for (int off = 1; off < 16; off <<= 1) { int u = __shfl_up(wv, off); if (t >= off) wv += u; }
        if (t < 16) ws[t] = wv;      // inclusive wave sums
    }
    __syncthreads();
    int waveoff = (t >= 64) ? ws[(t >> 6) - 1] : 0;
    int excl = x - v + waveoff + partx[b];
    if (i < NN) { rowstart[i] = excl; cursor[i] = excl; }
}

__global__ void k_scatter(const int* __restrict__ src, const int* __restrict__ dst,
                          int* __restrict__ cursor, int* __restrict__ csr) {
    int e = blockIdx.x * blockDim.x + threadIdx.x;
    if (e < E_CNT) {
        int p = atomicAdd(&cursor[dst[e]], 1);
        csr[p] = src[e];
    }
}

// ---------- layer 0: gat_conv(0) == conv_bias exactly (self-loops guarantee denom>=1) ----------
__global__ void k_layer0(const float* __restrict__ h0, const float* __restrict__ bias,
                         const float* __restrict__ alphas, float* __restrict__ out) {
    int i = blockIdx.x * blockDim.x + threadIdx.x;
    if (i >= NN * HID) return;
    int ch = i & (HID - 1);
    float g = eluf(bias[ch]);
    out[i] = 2.f * g + alphas[NLAYER - 1] * h0[i];
}

// ---------- GAT aggregation + Clenshaw epilogue: one wave per node ----------
__global__ __launch_bounds__(256) void k_agg(
    const unsigned short* __restrict__ hpb, const float* __restrict__ aS, const float* __restrict__ aD,
    const int* __restrict__ rowstart, const int* __restrict__ csr,
    const float* __restrict__ bias, const float* __restrict__ h0,
    const float* __restrict__ sl, const float* __restrict__ alphas, int aidx,
    float* __restrict__ hnew) {
    __shared__ int slds[4][CAP];
    const int wave = threadIdx.x >> 6;
    const int lane = threadIdx.x & 63;
    const int n    = blockIdx.x * 4 + wave;      // grid = NN/4 exactly
    const int rs   = rowstart[n];
    const int deg  = rowstart[n + 1] - rs;
    const int cnt  = deg < CAP ? deg : CAP;

    for (int j = lane; j < cnt; j += 64) slds[wave][j] = csr[rs + j];
    __syncthreads();

    // ---- softmax phase: lane = (slot<<3) | h ; 8 slots stride the edge list ----
    const int h    = lane & 7;
    const int slot = lane >> 3;
    const float adst_h = aD[n * NHEAD + h];

    float m = -1e30f;
    for (int j = slot; j < deg; j += 8) {
        int s = (j < CAP) ? slds[wave][j] : csr[rs + j];
        m = fmaxf(m, lrelu(aS[s * NHEAD + h] + adst_h));
    }
    float den = 0.f;
    for (int j = slot; j < deg; j += 8) {
        int s = (j < CAP) ? slds[wave][j] : csr[rs + j];
        den += __expf(lrelu(aS[s * NHEAD + h] + adst_h) - m);
    }
    // merge 8 slots per head (lanes differing in bits 3..5)
#pragma unroll
    for (int off = 8; off < 64; off <<= 1) {
        float mo = __shfl_xor(m, off);
        float dn = __shfl_xor(den, off);
        float mn = fmaxf(m, mo);
        den = den * __expf(m - mn) + dn * __expf(mo - mn);
        m = mn;
    }
    // self-loop logit (every lane of a head computes identically)
    {
        float e0 = lrelu(aS[n * NHEAD + h] + adst_h);
        float mn = fmaxf(m, e0);
        den = den * __expf(m - mn) + __expf(e0 - mn);
        m = mn;
    }

    // ---- transpose state to channel layout: lane handles channels 2*lane, 2*lane+1 ----
    const int hh = lane >> 3;                   // head of my channels
    const float mh  = __shfl(m, hh);
    const float dh  = __shfl(den, hh);
    const float ad2 = __shfl(adst_h, hh);       // aD[n*8+hh]
    const float inv = 1.f / (dh + 1e-16f);

    const unsigned int* hp4 = (const unsigned int*)hpb;
    float w0 = __expf(lrelu(aS[n * NHEAD + hh] + ad2) - mh) * inv;
    float2 v0 = bf2f2(hp4[(size_t)n * 64 + lane]);
    float accx = v0.x * w0, accy = v0.y * w0;
    for (int j = 0; j < deg; ++j) {
        int s = (j < CAP) ? slds[wave][j] : csr[rs + j];
        float wg = __expf(lrelu(aS[s * NHEAD + hh] + ad2) - mh) * inv;
        float2 v = bf2f2(hp4[(size_t)s * 64 + lane]);
        accx += v.x * wg; accy += v.y * wg;
    }

    // ---- epilogue: +bias, elu, 2*g - second_last + alpha*h0 ----
    const int ch = lane * 2;
    float g0 = eluf(accx + bias[ch]);
    float g1 = eluf(accy + bias[ch + 1]);
    const float ac = alphas[aidx];
    const float2 s2 = ((const float2*)sl)[(size_t)n * 64 + lane];
    const float2 hv = ((const float2*)h0)[(size_t)n * 64 + lane];
    float2 o;
    o.x = 2.f * g0 - s2.x + ac * hv.x;
    o.y = 2.f * g1 - s2.y + ac * hv.y;
    ((float2*)hnew)[(size_t)n * 64 + lane] = o;
}

// ---------- final: [NN,128] @ [128,40] + bias, log_softmax ----------
__global__ __launch_bounds__(64) void k_out(const float* __restrict__ t,
                                            const float* __restrict__ w,
                                            const float* __restrict__ b,
                                            float* __restrict__ out) {
    const int n = blockIdx.x;
    const int lane = threadIdx.x;
    float acc = 0.f;
    if (lane < OUT_C) {
        for (int k = 0; k < HID; ++k) acc += t[(size_t)n * HID + k] * w[k * OUT_C + lane];
        acc += b[lane];
    }
    float v = (lane < OUT_C) ? acc : -INFINITY;
    for (int off = 32; off; off >>= 1) v = fmaxf(v, __shfl_down(v, off));
    float mx = __shfl(v, 0);
    float ex = (lane < OUT_C) ? __expf(acc - mx) : 0.f;
    float sv = ex;
    for (int off = 32; off; off >>= 1) sv += __shfl_down(sv, off);
    float lse = logf(__shfl(sv, 0));
    if (lane < OUT_C) out[(size_t)n * OUT_C + lane] = acc - mx - lse;
}

// ---------- host ----------
extern "C" void kernel_launch(void* const* d_in, const int* in_sizes, int n_in,
                              void* d_out, int out_size, void* d_ws, size_t ws_size,
                              hipStream_t stream) {
    const float* x      = (const float*)d_in[0];
    const int*   ei     = (const int*)  d_in[1];
    const float* fc0w   = (const float*)d_in[2];
    const float* fc0b   = (const float*)d_in[3];
    const float* linw   = (const float*)d_in[4];
    const float* attS   = (const float*)d_in[5];
    const float* attD   = (const float*)d_in[6];
    const float* cbias  = (const float*)d_in[7];
    const float* alphas = (const float*)d_in[8];
    const float* fc1w   = (const float*)d_in[9];
    const float* fc1b   = (const float*)d_in[10];
    float* out = (float*)d_out;

    char* p = (char*)d_ws;
    auto alloc = [&](size_t bytes) { void* q = (void*)p; p += (bytes + 255) / 256 * 256; return q; };
    float* h0  = (float*)alloc((size_t)NN * HID * 4);
    float* bA  = (float*)alloc((size_t)NN * HID * 4);
    float* bB  = (float*)alloc((size_t)NN * HID * 4);
    float* bC  = (float*)alloc((size_t)NN * HID * 4);
    unsigned short* hpb = (unsigned short*)alloc((size_t)NN * HID * 2);
    float* aSb = (float*)alloc((size_t)NN * NHEAD * 4);
    float* aDb = (float*)alloc((size_t)NN * NHEAD * 4);
    int* deg      = (int*)alloc((size_t)(NN + 1) * 4);
    int* rowstart = (int*)alloc((size_t)(NN + 1) * 4);
    int* cursor   = (int*)alloc((size_t)NN * 4);
    int* part     = (int*)alloc(64 * 4);
    int* csr      = (int*)alloc((size_t)E_CNT * 4);

    const int* esrc = ei;
    const int* edst = ei + E_CNT;
    const int NB = (NN + 1023) / 1024;   // 49

    // CSR build (graph identical across layers)
    hipMemsetAsync(deg, 0, (size_t)NN * 4, stream);
    k_hist<<<(E_CNT + 255) / 256, 256, 0, stream>>>(edst, deg);
    k_part<<<NB, 1024, 0, stream>>>(deg, part);
    k_scanpart<<<1, 64, 0, stream>>>(part, rowstart, NB);
    k_scanblk<<<NB, 1024, 0, stream>>>(deg, part, rowstart, cursor);
    k_scatter<<<(E_CNT + 255) / 256, 256, 0, stream>>>(esrc, edst, cursor, csr);

    // h0 = x @ fc0_w + fc0_b
    k_gemm128<IN_C, 0><<<(NN + 63) / 64, 256, 0, stream>>>(x, fc0w, fc0b, h0, nullptr);

    // second_last = 0 ; layer 0 shortcut (conv(0) == bias exactly)
    hipMemsetAsync(bB, 0, (size_t)NN * HID * 4, stream);
    k_layer0<<<(NN * HID + 255) / 256, 256, 0, stream>>>(h0, cbias, alphas, bA);

    float* last = bA; float* sl = bB; float* nxt = bC;
    for (int i = 1; i < NLAYER; ++i) {
        k_gemm128<HID, 1><<<(NN + 63) / 64, 256, 0, stream>>>(last, linw + (size_t)i * HID * HID, nullptr, nullptr, hpb);
        k_att<<<(NN * NHEAD + 255) / 256, 256, 0, stream>>>(hpb, attS + i * NHEAD * CPH, attD + i * NHEAD * CPH, aSb, aDb);
        k_agg<<<NN / 4, 256, 0, stream>>>(hpb, aSb, aDb, rowstart, csr,
                                          cbias + i * HID, h0, sl, alphas, NLAYER - 1 - i, nxt);
        float* tmp = sl; sl = last; last = nxt; nxt = tmp;
    }

    k_out<<<NN, 64, 0, stream>>>(last, fc1w, fc1b, out);
}

// Round 3
// 748.878 us; speedup vs baseline: 2.0224x; 1.3190x over previous
//
#include <hip/hip_runtime.h>
#include <math.h>

#define NN      50000
#define E_CNT   800000
#define IN_C    512
#define HID     128
#define OUT_C   40
#define NHEAD   8
#define CPH     16
#define NLAYER  5
#define NEG     0.2f
#define CAP     128   // LDS-staged neighbor cap per node (random graph: deg~Pois(16))

typedef __attribute__((ext_vector_type(8))) short bf16x8;
typedef __attribute__((ext_vector_type(4))) float f32x4;

__device__ __forceinline__ float lrelu(float x) { return x > 0.f ? x : NEG * x; }
__device__ __forceinline__ float eluf(float x)  { return x > 0.f ? x : expm1f(x); }

__device__ __forceinline__ float2 bf2f2(unsigned int u) {
    union { unsigned int a; float f; } lo, hi;
    lo.a = u << 16; hi.a = u & 0xffff0000u;
    return make_float2(lo.f, hi.f);
}
__device__ __forceinline__ unsigned short f2bf(float f) {
    union { float f; unsigned int u; } v; v.f = f;
    return (unsigned short)((v.u + 0x7fffu + ((v.u >> 16) & 1u)) >> 16);
}
__device__ __forceinline__ unsigned int pack2(float a, float b) {
    return ((unsigned int)f2bf(b) << 16) | f2bf(a);
}

// async 16B global -> LDS (dest = wave-uniform base + lane*16)
__device__ __forceinline__ void gl2lds16(const void* g, void* l) {
    __builtin_amdgcn_global_load_lds(
        (const __attribute__((address_space(1))) unsigned int*)g,
        (__attribute__((address_space(3))) unsigned int*)l, 16, 0, 0);
}

// ---------- fp32 -> bf16 convert (4 elems/thread) ----------
__global__ void k_cvt(const float* __restrict__ in, unsigned int* __restrict__ outp, int n4) {
    int i = blockIdx.x * blockDim.x + threadIdx.x;
    if (i >= n4) return;
    float4 v = ((const float4*)in)[i];
    ((uint2*)outp)[i] = make_uint2(pack2(v.x, v.y), pack2(v.z, v.w));
}

// ---------- weight transpose+convert: w[K][128] fp32 -> wt[128][K] bf16 ----------
__global__ __launch_bounds__(256) void k_wt(const float* __restrict__ w,
                                            unsigned short* __restrict__ wt, int K) {
    __shared__ float t[32][33];
    int k0 = blockIdx.x * 32, n0 = blockIdx.y * 32;
    int tx = threadIdx.x & 31, ty = threadIdx.x >> 5;   // 32 x 8
    for (int r = ty; r < 32; r += 8) t[r][tx] = w[(size_t)(k0 + r) * HID + n0 + tx];
    __syncthreads();
    for (int r = ty; r < 32; r += 8) wt[(size_t)(n0 + r) * K + k0 + tx] = f2bf(t[tx][r]);
}

// ---------- MFMA GEMM: ab[NN][K] bf16  @  wt[128][K] bf16 (B^T)  -> [NN][128] ----------
// m97 structure: 128x128 tile, BK=32, 4 waves in 2x2 quadrants of 64x64.
// OUT_BF16=0: out_f = ab@wt^T + bias (fp32). OUT_BF16=1: out_b = bf16(ab@wt^T).
template<int K, int OUT_BF16>
__global__ __launch_bounds__(256) void k_mgemm(const unsigned short* __restrict__ ab,
                                               const unsigned short* __restrict__ wt,
                                               const float* __restrict__ bias,
                                               float* __restrict__ out_f,
                                               unsigned short* __restrict__ out_b) {
    __shared__ unsigned short As[128 * 32];
    __shared__ unsigned short Bs[128 * 32];
    const int tid  = threadIdx.x;
    const int w    = tid >> 6, lane = tid & 63;
    const int wr   = w & 1, wc = w >> 1;
    const int row0 = blockIdx.x * 128;
    f32x4 acc[4][4] = {};

    const int rs = lane >> 2;            // 0..15: row within a 16-row staging group
    const int ko = (lane & 3) * 8;       // bf16 elems: 16B chunk within a 64B row

    for (int k0 = 0; k0 < K; k0 += 32) {
#pragma unroll
        for (int h = 0; h < 2; ++h) {
            int r = w * 32 + h * 16;                       // staging group base row
            int grow = row0 + r + rs; if (grow >= NN) grow = NN - 1;
            gl2lds16(ab + (size_t)grow * K + k0 + ko, &As[r * 32]);
            gl2lds16(wt + (size_t)(r + rs) * K + k0 + ko, &Bs[r * 32]);
        }
        __syncthreads();
        const int fr = lane & 15, fq = lane >> 4;
        bf16x8 af[4], bfr[4];
#pragma unroll
        for (int t = 0; t < 4; ++t) {
            af[t]  = *(const bf16x8*)&As[(wr * 64 + t * 16 + fr) * 32 + fq * 8];
            bfr[t] = *(const bf16x8*)&Bs[(wc * 64 + t * 16 + fr) * 32 + fq * 8];
        }
#pragma unroll
        for (int tm = 0; tm < 4; ++tm)
#pragma unroll
            for (int tn = 0; tn < 4; ++tn)
                acc[tm][tn] = __builtin_amdgcn_mfma_f32_16x16x32_bf16(af[tm], bfr[tn], acc[tm][tn], 0, 0, 0);
        __syncthreads();
    }

    // epilogue: C/D map col=lane&15, row=(lane>>4)*4+reg  [m89-verified]
    const int cl = lane & 15, rq = (lane >> 4) * 4;
#pragma unroll
    for (int tm = 0; tm < 4; ++tm)
#pragma unroll
        for (int tn = 0; tn < 4; ++tn) {
            int col = wc * 64 + tn * 16 + cl;
            int rbase = row0 + wr * 64 + tm * 16 + rq;
            f32x4 a4 = acc[tm][tn];
#pragma unroll
            for (int rg = 0; rg < 4; ++rg) {
                int row = rbase + rg;
                if (row < NN) {
                    if (OUT_BF16) out_b[(size_t)row * HID + col] = f2bf(a4[rg]);
                    else          out_f[(size_t)row * HID + col] = a4[rg] + bias[col];
                }
            }
        }
}

// ---------- attention coefficients from bf16 hp ----------
__global__ void k_att(const unsigned short* __restrict__ hpb,
                      const float* __restrict__ attS, const float* __restrict__ attD,
                      float* __restrict__ aS, float* __restrict__ aD) {
    int i = blockIdx.x * blockDim.x + threadIdx.x;   // n*8 + h
    if (i >= NN * NHEAD) return;
    int h = i & 7;
    const unsigned int* row = (const unsigned int*)(hpb + (size_t)(i >> 3) * HID + h * CPH);
    float s = 0.f, d = 0.f;
#pragma unroll
    for (int cc = 0; cc < 8; ++cc) {
        float2 v = bf2f2(row[cc]);
        s += v.x * attS[h * CPH + 2 * cc] + v.y * attS[h * CPH + 2 * cc + 1];
        d += v.x * attD[h * CPH + 2 * cc] + v.y * attD[h * CPH + 2 * cc + 1];
    }
    aS[i] = s; aD[i] = d;
}

// ---------- CSR build ----------
__global__ void k_hist(const int* __restrict__ dst, int* __restrict__ deg) {
    int e = blockIdx.x * blockDim.x + threadIdx.x;
    if (e < E_CNT) atomicAdd(&deg[dst[e]], 1);
}

__global__ __launch_bounds__(1024) void k_part(const int* __restrict__ deg, int* __restrict__ part) {
    int i = blockIdx.x * 1024 + threadIdx.x;
    int v = (i < NN) ? deg[i] : 0;
    for (int off = 32; off; off >>= 1) v += __shfl_down(v, off);
    __shared__ int ws[16];
    if ((threadIdx.x & 63) == 0) ws[threadIdx.x >> 6] = v;
    __syncthreads();
    if (threadIdx.x < 16) {
        int t = ws[threadIdx.x];
        for (int off = 8; off; off >>= 1) t += __shfl_down(t, off);
        if (threadIdx.x == 0) part[blockIdx.x] = t;
    }
}

__global__ void k_scanpart(int* __restrict__ part, int* __restrict__ rowstart, int nb) {
    int t = threadIdx.x;             // 64 threads, nb<=64
    int v = (t < nb) ? part[t] : 0;
    int x = v;
    for (int off = 1; off < 64; off <<= 1) { int u = __shfl_up(x, off); if (t >= off) x += u; }
    if (t < nb) part[t] = x - v;     // exclusive
    if (t == nb - 1) rowstart[NN] = x;
}

__global__ __launch_bounds__(1024) void k_scanblk(const int* __restrict__ deg,
                                                  const int* __restrict__ partx,
                                                  int* __restrict__ rowstart,
                                                  int* __restrict__ cursor) {
    int b = blockIdx.x, t = threadIdx.x, i = b * 1024 + t;
    int v = (i < NN) ? deg[i] : 0;
    int x = v;
    for (int off = 1; off < 64; off <<= 1) { int u = __shfl_up(x, off); if ((t & 63) >= off) x += u; }
    __shared__ int ws[16];
    if ((t & 63) == 63) ws[t >> 6] = x;
    __syncthreads();
    if (t < 64) {
        int wv = (t < 16) ? ws[t] : 0;
        for (int off = 1; off < 16; off <<= 1) { int u = __shfl_up(wv, off); if (t >= off) wv += u; }
        if (t < 16) ws[t] = wv;
    }
    __syncthreads();
    int waveoff = (t >= 64) ? ws[(t >> 6) - 1] : 0;
    int excl = x - v + waveoff + partx[b];
    if (i < NN) { rowstart[i] = excl; cursor[i] = excl; }
}

__global__ void k_scatter(const int* __restrict__ src, const int* __restrict__ dst,
                          int* __restrict__ cursor, int* __restrict__ csr) {
    int e = blockIdx.x * blockDim.x + threadIdx.x;
    if (e < E_CNT) {
        int p = atomicAdd(&cursor[dst[e]], 1);
        csr[p] = src[e];
    }
}

// ---------- layer 0: gat_conv(0) == conv_bias exactly ----------
__global__ void k_layer0(const float* __restrict__ h0, const float* __restrict__ bias,
                         const float* __restrict__ alphas,
                         float* __restrict__ out, unsigned int* __restrict__ outb) {
    int i = blockIdx.x * blockDim.x + threadIdx.x;   // pair index
    if (i >= NN * 64) return;
    int ch = (i & 63) * 2;
    float a4 = alphas[NLAYER - 1];
    float2 h = ((const float2*)h0)[i];
    float v0 = 2.f * eluf(bias[ch])     + a4 * h.x;
    float v1 = 2.f * eluf(bias[ch + 1]) + a4 * h.y;
    ((float2*)out)[i] = make_float2(v0, v1);
    outb[i] = pack2(v0, v1);
}

// ---------- GAT aggregation + Clenshaw epilogue: one wave per node ----------
__global__ __launch_bounds__(256) void k_agg(
    const unsigned short* __restrict__ hpb, const float* __restrict__ aS, const float* __restrict__ aD,
    const int* __restrict__ rowstart, const int* __restrict__ csr,
    const float* __restrict__ bias, const float* __restrict__ h0,
    const float* __restrict__ sl, const float* __restrict__ alphas, int aidx,
    float* __restrict__ hnew, unsigned int* __restrict__ hnewb) {
    __shared__ int   slds[4][CAP];
    __shared__ float wlds[4][CAP][NHEAD];
    const int wave = threadIdx.x >> 6;
    const int lane = threadIdx.x & 63;
    const int n    = blockIdx.x * 4 + wave;      // grid = NN/4 exactly
    const int rsb  = rowstart[n];
    const int deg  = rowstart[n + 1] - rsb;
    const int cnt  = deg < CAP ? deg : CAP;

    for (int j = lane; j < cnt; j += 64) slds[wave][j] = csr[rsb + j];
    __syncthreads();

    // ---- softmax stats: lane = (slot<<3) | h ----
    const int h    = lane & 7;
    const int slot = lane >> 3;
    const float adst_h = aD[n * NHEAD + h];

    float m = -1e30f;
    for (int j = slot; j < deg; j += 8) {
        int s = (j < CAP) ? slds[wave][j] : csr[rsb + j];
        m = fmaxf(m, lrelu(aS[s * NHEAD + h] + adst_h));
    }
    float den = 0.f;
    for (int j = slot; j < deg; j += 8) {
        int s = (j < CAP) ? slds[wave][j] : csr[rsb + j];
        den += __expf(lrelu(aS[s * NHEAD + h] + adst_h) - m);
    }
#pragma unroll
    for (int off = 8; off < 64; off <<= 1) {
        float mo = __shfl_xor(m, off);
        float dn = __shfl_xor(den, off);
        float mn = fmaxf(m, mo);
        den = den * __expf(m - mn) + dn * __expf(mo - mn);
        m = mn;
    }
    {   // self-loop logit
        float e0 = lrelu(aS[n * NHEAD + h] + adst_h);
        float mn = fmaxf(m, e0);
        den = den * __expf(m - mn) + __expf(e0 - mn);
        m = mn;
    }
    const float inv = 1.f / (den + 1e-16f);

    // ---- materialize normalized per-(edge,head) weights (one exp per edge-head) ----
    for (int j = slot; j < cnt; j += 8) {
        int s = slds[wave][j];
        wlds[wave][j][h] = __expf(lrelu(aS[s * NHEAD + h] + adst_h) - m) * inv;
    }
    __syncthreads();

    // ---- weighted gather: lane handles channels 2*lane, 2*lane+1 ----
    const int hh = lane >> 3;
    const float mh   = __shfl(m, hh);
    const float invh = __shfl(inv, hh);
    const float ad2  = __shfl(adst_h, hh);

    const unsigned int* hp4 = (const unsigned int*)hpb;
    float w0 = __expf(lrelu(aS[n * NHEAD + hh] + ad2) - mh) * invh;
    float2 v0 = bf2f2(hp4[(size_t)n * 64 + lane]);
    float accx = v0.x * w0, accy = v0.y * w0;
    for (int j = 0; j < deg; ++j) {
        float wg;
        int s;
        if (j < CAP) { s = slds[wave][j]; wg = wlds[wave][j][hh]; }
        else { s = csr[rsb + j]; wg = __expf(lrelu(aS[s * NHEAD + hh] + ad2) - mh) * invh; }
        float2 v = bf2f2(hp4[(size_t)s * 64 + lane]);
        accx += v.x * wg; accy += v.y * wg;
    }

    // ---- epilogue ----
    const int ch = lane * 2;
    float g0 = eluf(accx + bias[ch]);
    float g1 = eluf(accy + bias[ch + 1]);
    const float ac = alphas[aidx];
    const float2 s2 = ((const float2*)sl)[(size_t)n * 64 + lane];
    const float2 hv = ((const float2*)h0)[(size_t)n * 64 + lane];
    float2 o;
    o.x = 2.f * g0 - s2.x + ac * hv.x;
    o.y = 2.f * g1 - s2.y + ac * hv.y;
    ((float2*)hnew)[(size_t)n * 64 + lane] = o;
    hnewb[(size_t)n * 64 + lane] = pack2(o.x, o.y);
}

// ---------- final: [NN,128] @ [128,40] + bias, log_softmax ----------
__global__ __launch_bounds__(64) void k_out(const float* __restrict__ t,
                                            const float* __restrict__ w,
                                            const float* __restrict__ b,
                                            float* __restrict__ out) {
    const int n = blockIdx.x;
    const int lane = threadIdx.x;
    float acc = 0.f;
    if (lane < OUT_C) {
        for (int k = 0; k < HID; ++k) acc += t[(size_t)n * HID + k] * w[k * OUT_C + lane];
        acc += b[lane];
    }
    float v = (lane < OUT_C) ? acc : -INFINITY;
    for (int off = 32; off; off >>= 1) v = fmaxf(v, __shfl_down(v, off));
    float mx = __shfl(v, 0);
    float ex = (lane < OUT_C) ? __expf(acc - mx) : 0.f;
    float sv = ex;
    for (int off = 32; off; off >>= 1) sv += __shfl_down(sv, off);
    float lse = logf(__shfl(sv, 0));
    if (lane < OUT_C) out[(size_t)n * OUT_C + lane] = acc - mx - lse;
}

// ---------- host ----------
extern "C" void kernel_launch(void* const* d_in, const int* in_sizes, int n_in,
                              void* d_out, int out_size, void* d_ws, size_t ws_size,
                              hipStream_t stream) {
    const float* x      = (const float*)d_in[0];
    const int*   ei     = (const int*)  d_in[1];
    const float* fc0w   = (const float*)d_in[2];
    const float* fc0b   = (const float*)d_in[3];
    const float* linw   = (const float*)d_in[4];
    const float* attS   = (const float*)d_in[5];
    const float* attD   = (const float*)d_in[6];
    const float* cbias  = (const float*)d_in[7];
    const float* alphas = (const float*)d_in[8];
    const float* fc1w   = (const float*)d_in[9];
    const float* fc1b   = (const float*)d_in[10];
    float* out = (float*)d_out;

    char* p = (char*)d_ws;
    auto alloc = [&](size_t bytes) { void* q = (void*)p; p += (bytes + 255) / 256 * 256; return q; };
    const size_t NNH = (size_t)NN * HID * 4;
    float* h0 = (float*)alloc(NNH);
    float* bA = (float*)alloc(NNH);
    float* bB = (float*)alloc(NNH);
    float* bC = (float*)alloc(NNH);
    unsigned short* xb = (unsigned short*)bB;   // alias: xb dead before bB/bC first written
    unsigned short* lastb = (unsigned short*)alloc((size_t)NN * HID * 2);
    unsigned short* hpb   = (unsigned short*)alloc((size_t)NN * HID * 2);
    float* aSb = (float*)alloc((size_t)NN * NHEAD * 4);
    float* aDb = (float*)alloc((size_t)NN * NHEAD * 4);
    unsigned short* WT0 = (unsigned short*)alloc((size_t)HID * IN_C * 2);
    unsigned short* WTL = (unsigned short*)alloc((size_t)4 * HID * HID * 2);
    int* deg      = (int*)alloc((size_t)(NN + 1) * 4);
    int* rowstart = (int*)alloc((size_t)(NN + 1) * 4);
    int* part     = (int*)alloc(64 * 4);
    int* csr      = (int*)alloc((size_t)E_CNT * 4);
    int* cursor   = deg;   // safe: k_scanblk reads deg[i] before writing cursor[i]; deg dead after

    const int* esrc = ei;
    const int* edst = ei + E_CNT;
    const int NB = (NN + 1023) / 1024;

    // CSR build
    hipMemsetAsync(deg, 0, (size_t)NN * 4, stream);
    k_hist<<<(E_CNT + 255) / 256, 256, 0, stream>>>(edst, deg);
    k_part<<<NB, 1024, 0, stream>>>(deg, part);
    k_scanpart<<<1, 64, 0, stream>>>(part, rowstart, NB);
    k_scanblk<<<NB, 1024, 0, stream>>>(deg, part, rowstart, cursor);
    k_scatter<<<(E_CNT + 255) / 256, 256, 0, stream>>>(esrc, edst, cursor, csr);

    // prep: x -> bf16, weights -> transposed bf16
    k_cvt<<<(NN * IN_C / 4 + 255) / 256, 256, 0, stream>>>(x, (unsigned int*)xb, NN * IN_C / 4);
    {
        dim3 g0(IN_C / 32, HID / 32);
        k_wt<<<g0, 256, 0, stream>>>(fc0w, WT0, IN_C);
        dim3 gl(HID / 32, HID / 32);
        for (int i = 1; i < NLAYER; ++i)
            k_wt<<<gl, 256, 0, stream>>>(linw + (size_t)i * HID * HID, WTL + (size_t)(i - 1) * HID * HID, HID);
    }

    const int GB = (NN + 127) / 128;   // 391
    // h0 = x @ fc0_w + fc0_b   (MFMA)
    k_mgemm<IN_C, 0><<<GB, 256, 0, stream>>>(xb, WT0, fc0b, h0, nullptr);

    // layer 0 shortcut; second_last = 0
    hipMemsetAsync(bB, 0, NNH, stream);
    k_layer0<<<(NN * 64 + 255) / 256, 256, 0, stream>>>(h0, cbias, alphas, bA, (unsigned int*)lastb);

    float* last = bA; float* sl = bB; float* nxt = bC;
    for (int i = 1; i < NLAYER; ++i) {
        k_mgemm<HID, 1><<<GB, 256, 0, stream>>>(lastb, WTL + (size_t)(i - 1) * HID * HID, nullptr, nullptr, hpb);
        k_att<<<(NN * NHEAD + 255) / 256, 256, 0, stream>>>(hpb, attS + i * NHEAD * CPH, attD + i * NHEAD * CPH, aSb, aDb);
        k_agg<<<NN / 4, 256, 0, stream>>>(hpb, aSb, aDb, rowstart, csr,
                                          cbias + i * HID, h0, sl, alphas, NLAYER - 1 - i,
                                          nxt, (unsigned int*)lastb);
        float* tmp = sl; sl = last; last = nxt; nxt = tmp;
    }

    k_out<<<NN, 64, 0, stream>>>(last, fc1w, fc1b, out);
}

// Round 4
// 607.409 us; speedup vs baseline: 2.4935x; 1.2329x over previous
//
#include <hip/hip_runtime.h>
#include <math.h>

#define NN      50000
#define E_CNT   800000
#define IN_C    512
#define HID     128
#define OUT_C   40
#define NHEAD   8
#define CPH     16
#define NLAYER  5
#define NEG     0.2f
#define CAP     64    // LDS edge cap per node (deg~Pois(16); tail handled via global fallback)

typedef __attribute__((ext_vector_type(8))) short bf16x8;
typedef __attribute__((ext_vector_type(4))) float f32x4;

__device__ __forceinline__ float lrelu(float x) { return x > 0.f ? x : NEG * x; }
__device__ __forceinline__ float eluf(float x)  { return x > 0.f ? x : expm1f(x); }

__device__ __forceinline__ float2 bf2f2(unsigned int u) {
    union { unsigned int a; float f; } lo, hi;
    lo.a = u << 16; hi.a = u & 0xffff0000u;
    return make_float2(lo.f, hi.f);
}
__device__ __forceinline__ unsigned short f2bf(float f) {
    union { float f; unsigned int u; } v; v.f = f;
    return (unsigned short)((v.u + 0x7fffu + ((v.u >> 16) & 1u)) >> 16);
}
__device__ __forceinline__ unsigned int pack2(float a, float b) {
    return ((unsigned int)f2bf(b) << 16) | f2bf(a);
}

// async 16B global -> LDS (dest = wave-uniform base + lane*16)
__device__ __forceinline__ void gl2lds16(const void* g, void* l) {
    __builtin_amdgcn_global_load_lds(
        (const __attribute__((address_space(1))) unsigned int*)g,
        (__attribute__((address_space(3))) unsigned int*)l, 16, 0, 0);
}

// ---------- weight transpose+convert: w[K][128] fp32 -> wt[128][K] bf16 (batched over z) ----------
__global__ __launch_bounds__(256) void k_wt(const float* __restrict__ w,
                                            unsigned short* __restrict__ wt, int K) {
    __shared__ float t[32][33];
    const float* ws = w + (size_t)blockIdx.z * K * HID;
    unsigned short* wd = wt + (size_t)blockIdx.z * K * HID;
    int k0 = blockIdx.x * 32, n0 = blockIdx.y * 32;
    int tx = threadIdx.x & 31, ty = threadIdx.x >> 5;   // 32 x 8
    for (int r = ty; r < 32; r += 8) t[r][tx] = ws[(size_t)(k0 + r) * HID + n0 + tx];
    __syncthreads();
    for (int r = ty; r < 32; r += 8) wd[(size_t)(n0 + r) * K + k0 + tx] = f2bf(t[tx][r]);
}

// ---------- MFMA GEMM: A[NN][K] @ wt[128][K]^T -> [NN][128] ----------
// m97 structure: 128x128 tile, BK=32, 4 waves in 2x2 quadrants of 64x64.
// A_F32=1: A is fp32, converted to bf16 during staging (no global_load_lds for A).
// EPI=0: out_b = bf16(A@W^T).  EPI=2: fused fc0+layer0: h0=acc+fc0b; bA=2*elu(cb0)+a4*h0; lastb=bf16(bA).
template<int K, int A_F32, int EPI>
__global__ __launch_bounds__(256) void k_mgemm(const void* __restrict__ aptr,
                                               const unsigned short* __restrict__ wt,
                                               const float* __restrict__ bias,
                                               const float* __restrict__ cb0,
                                               const float* __restrict__ alphas,
                                               float* __restrict__ out_f,
                                               float* __restrict__ out_f2,
                                               unsigned short* __restrict__ out_b) {
    __shared__ unsigned short As[128 * 32];
    __shared__ unsigned short Bs[128 * 32];
    const int tid  = threadIdx.x;
    const int w    = tid >> 6, lane = tid & 63;
    const int wr   = w & 1, wc = w >> 1;
    const int row0 = blockIdx.x * 128;
    f32x4 acc[4][4] = {};

    const int rs = lane >> 2;            // 0..15: row within a 16-row staging group
    const int ko = (lane & 3) * 8;       // elem offset: 16B(bf16x8) chunk within a row

    for (int k0 = 0; k0 < K; k0 += 32) {
#pragma unroll
        for (int h = 0; h < 2; ++h) {
            int r = w * 32 + h * 16;
            int grow = row0 + r + rs; if (grow >= NN) grow = NN - 1;
            if (A_F32) {
                const float* src = (const float*)aptr + (size_t)grow * K + k0 + ko;
                float4 v0 = *(const float4*)src;
                float4 v1 = *(const float4*)(src + 4);
                uint4 pk;
                pk.x = pack2(v0.x, v0.y); pk.y = pack2(v0.z, v0.w);
                pk.z = pack2(v1.x, v1.y); pk.w = pack2(v1.z, v1.w);
                *(uint4*)&As[(r + rs) * 32 + ko] = pk;
            } else {
                gl2lds16((const unsigned short*)aptr + (size_t)grow * K + k0 + ko, &As[r * 32]);
            }
            gl2lds16(wt + (size_t)(r + rs) * K + k0 + ko, &Bs[r * 32]);
        }
        __syncthreads();
        const int fr = lane & 15, fq = lane >> 4;
        bf16x8 af[4], bfr[4];
#pragma unroll
        for (int t = 0; t < 4; ++t) {
            af[t]  = *(const bf16x8*)&As[(wr * 64 + t * 16 + fr) * 32 + fq * 8];
            bfr[t] = *(const bf16x8*)&Bs[(wc * 64 + t * 16 + fr) * 32 + fq * 8];
        }
#pragma unroll
        for (int tm = 0; tm < 4; ++tm)
#pragma unroll
            for (int tn = 0; tn < 4; ++tn)
                acc[tm][tn] = __builtin_amdgcn_mfma_f32_16x16x32_bf16(af[tm], bfr[tn], acc[tm][tn], 0, 0, 0);
        __syncthreads();
    }

    // epilogue: C/D map col=lane&15, row=(lane>>4)*4+reg
    const int cl = lane & 15, rq = (lane >> 4) * 4;
    const float a4 = (EPI == 2) ? alphas[NLAYER - 1] : 0.f;
#pragma unroll
    for (int tm = 0; tm < 4; ++tm)
#pragma unroll
        for (int tn = 0; tn < 4; ++tn) {
            int col = wc * 64 + tn * 16 + cl;
            int rbase = row0 + wr * 64 + tm * 16 + rq;
            f32x4 a4v = acc[tm][tn];
            float bcol = (EPI == 2) ? bias[col] : 0.f;
            float ecol = (EPI == 2) ? 2.f * eluf(cb0[col]) : 0.f;
#pragma unroll
            for (int rg = 0; rg < 4; ++rg) {
                int row = rbase + rg;
                if (row < NN) {
                    if (EPI == 0) {
                        out_b[(size_t)row * HID + col] = f2bf(a4v[rg]);
                    } else {
                        float h0v = a4v[rg] + bcol;
                        out_f[(size_t)row * HID + col] = h0v;
                        float bAv = ecol + a4 * h0v;
                        out_f2[(size_t)row * HID + col] = bAv;
                        out_b[(size_t)row * HID + col] = f2bf(bAv);
                    }
                }
            }
        }
}

// ---------- attention coefficients from bf16 hp ----------
__global__ void k_att(const unsigned short* __restrict__ hpb,
                      const float* __restrict__ attS, const float* __restrict__ attD,
                      float* __restrict__ aS, float* __restrict__ aD) {
    int i = blockIdx.x * blockDim.x + threadIdx.x;   // n*8 + h
    if (i >= NN * NHEAD) return;
    int h = i & 7;
    const unsigned int* row = (const unsigned int*)(hpb + (size_t)(i >> 3) * HID + h * CPH);
    float s = 0.f, d = 0.f;
#pragma unroll
    for (int cc = 0; cc < 8; ++cc) {
        float2 v = bf2f2(row[cc]);
        s += v.x * attS[h * CPH + 2 * cc] + v.y * attS[h * CPH + 2 * cc + 1];
        d += v.x * attD[h * CPH + 2 * cc] + v.y * attD[h * CPH + 2 * cc + 1];
    }
    aS[i] = s; aD[i] = d;
}

// ---------- CSR build ----------
__global__ void k_hist(const int* __restrict__ dst, int* __restrict__ deg) {
    int e = blockIdx.x * blockDim.x + threadIdx.x;
    if (e < E_CNT) atomicAdd(&deg[dst[e]], 1);
}

__global__ __launch_bounds__(1024) void k_part(const int* __restrict__ deg, int* __restrict__ part) {
    int i = blockIdx.x * 1024 + threadIdx.x;
    int v = (i < NN) ? deg[i] : 0;
    for (int off = 32; off; off >>= 1) v += __shfl_down(v, off);
    __shared__ int ws[16];
    if ((threadIdx.x & 63) == 0) ws[threadIdx.x >> 6] = v;
    __syncthreads();
    if (threadIdx.x < 16) {
        int t = ws[threadIdx.x];
        for (int off = 8; off; off >>= 1) t += __shfl_down(t, off);
        if (threadIdx.x == 0) part[blockIdx.x] = t;
    }
}

__global__ void k_scanpart(int* __restrict__ part, int* __restrict__ rowstart, int nb) {
    int t = threadIdx.x;             // 64 threads, nb<=64
    int v = (t < nb) ? part[t] : 0;
    int x = v;
    for (int off = 1; off < 64; off <<= 1) { int u = __shfl_up(x, off); if (t >= off) x += u; }
    if (t < nb) part[t] = x - v;     // exclusive
    if (t == nb - 1) rowstart[NN] = x;
}

__global__ __launch_bounds__(1024) void k_scanblk(const int* __restrict__ deg,
                                                  const int* __restrict__ partx,
                                                  int* __restrict__ rowstart,
                                                  int* __restrict__ cursor) {
    int b = blockIdx.x, t = threadIdx.x, i = b * 1024 + t;
    int v = (i < NN) ? deg[i] : 0;
    int x = v;
    for (int off = 1; off < 64; off <<= 1) { int u = __shfl_up(x, off); if ((t & 63) >= off) x += u; }
    __shared__ int ws[16];
    if ((t & 63) == 63) ws[t >> 6] = x;
    __syncthreads();
    if (t < 64) {
        int wv = (t < 16) ? ws[t] : 0;
        for (int off = 1; off < 16; off <<= 1) { int u = __shfl_up(wv, off); if (t >= off) wv += u; }
        if (t < 16) ws[t] = wv;
    }
    __syncthreads();
    int waveoff = (t >= 64) ? ws[(t >> 6) - 1] : 0;
    int excl = x - v + waveoff + partx[b];
    if (i < NN) { rowstart[i] = excl; cursor[i] = excl; }
}

__global__ void k_scatter(const int* __restrict__ src, const int* __restrict__ dst,
                          int* __restrict__ cursor, int* __restrict__ csr) {
    int e = blockIdx.x * blockDim.x + threadIdx.x;
    if (e < E_CNT) {
        int p = atomicAdd(&cursor[dst[e]], 1);
        csr[p] = src[e];
    }
}

// ---------- GAT aggregation + Clenshaw epilogue: one wave per node ----------
// Single aS sweep (logits in regs), unnormalized weights + denom in one pass,
// 2-edge/iter uint2 gather (32 lanes/row), post-normalize.
__global__ __launch_bounds__(256) void k_agg(
    const unsigned short* __restrict__ hpb, const float* __restrict__ aS, const float* __restrict__ aD,
    const int* __restrict__ rowstart, const int* __restrict__ csr,
    const float* __restrict__ bias, const float* __restrict__ h0,
    const float* __restrict__ sl, const float* __restrict__ alphas, int aidx, int sl_zero,
    float* __restrict__ hnew, unsigned int* __restrict__ hnewb) {
    __shared__ int   slds[4][CAP];
    __shared__ float wlds[4][CAP][NHEAD];
    const int wave = threadIdx.x >> 6;
    const int lane = threadIdx.x & 63;
    const int n    = blockIdx.x * 4 + wave;      // grid = NN/4 exactly
    const int rsb  = rowstart[n];
    const int deg  = rowstart[n + 1] - rsb;
    const int cnt  = deg < CAP ? deg : CAP;

    for (int j = lane; j < cnt; j += 64) slds[wave][j] = csr[rsb + j];
    __syncthreads();

    // ---- stats layout: lane = slot*8 + h ; 8 slots stride the edge list ----
    const int h    = lane & 7;
    const int slot = lane >> 3;
    const float adst = aD[n * NHEAD + h];

    // one sweep: logits into registers, running max
    float ev[8];
    float m = -1e30f;
#pragma unroll
    for (int t = 0; t < 8; ++t) {
        int j = slot + t * 8;
        if (j < cnt) {
            int s = slds[wave][j];
            float e = lrelu(aS[s * NHEAD + h] + adst);
            ev[t] = e;
            m = fmaxf(m, e);
        }
    }
    for (int j = CAP + slot; j < deg; j += 8) {              // overflow tail (rare)
        int s = csr[rsb + j];
        m = fmaxf(m, lrelu(aS[s * NHEAD + h] + adst));
    }
#pragma unroll
    for (int off = 8; off < 64; off <<= 1) m = fmaxf(m, __shfl_xor(m, off));
    const float e0 = lrelu(aS[n * NHEAD + h] + adst);        // self-loop logit
    m = fmaxf(m, e0);

    // unnormalized weights + denom
    float den = 0.f;
#pragma unroll
    for (int t = 0; t < 8; ++t) {
        int j = slot + t * 8;
        if (j < cnt) {
            float wv = __expf(ev[t] - m);
            wlds[wave][j][h] = wv;
            den += wv;
        }
    }
    for (int j = CAP + slot; j < deg; j += 8) {              // overflow tail
        int s = csr[rsb + j];
        den += __expf(lrelu(aS[s * NHEAD + h] + adst) - m);
    }
#pragma unroll
    for (int off = 8; off < 64; off <<= 1) den += __shfl_xor(den, off);
    const float w0 = __expf(e0 - m);
    den += w0;
    const float dinv = 1.f / (den + 1e-16f);
    __syncthreads();

    // ---- gather: lane = half*32 + l ; l covers channels 4l..4l+3 (head l>>2) ----
    const int l    = lane & 31;
    const int half = lane >> 5;
    const int hh   = l >> 2;
    const float mh  = __shfl(m, hh);
    const float w0h = __shfl(w0, hh);
    const float dih = __shfl(dinv, hh);
    const float adh = __shfl(adst, hh);

    float a0 = 0.f, a1 = 0.f, a2 = 0.f, a3 = 0.f;
    if (half == 0) {
        uint2 u = *(const uint2*)(hpb + (size_t)n * HID + 4 * l);
        float2 p = bf2f2(u.x), q = bf2f2(u.y);
        a0 = w0h * p.x; a1 = w0h * p.y; a2 = w0h * q.x; a3 = w0h * q.y;
    }
    if (deg <= CAP) {
#pragma unroll 4
        for (int j = half; j < deg; j += 2) {
            int s = slds[wave][j];
            float wv = wlds[wave][j][hh];
            uint2 u = *(const uint2*)(hpb + (size_t)s * HID + 4 * l);
            float2 p = bf2f2(u.x), q = bf2f2(u.y);
            a0 += wv * p.x; a1 += wv * p.y; a2 += wv * q.x; a3 += wv * q.y;
        }
    } else {
        for (int j = half; j < deg; j += 2) {
            int s; float wv;
            if (j < CAP) { s = slds[wave][j]; wv = wlds[wave][j][hh]; }
            else { s = csr[rsb + j]; wv = __expf(lrelu(aS[s * NHEAD + hh] + adh) - mh); }
            uint2 u = *(const uint2*)(hpb + (size_t)s * HID + 4 * l);
            float2 p = bf2f2(u.x), q = bf2f2(u.y);
            a0 += wv * p.x; a1 += wv * p.y; a2 += wv * q.x; a3 += wv * q.y;
        }
    }
    a0 += __shfl_xor(a0, 32); a1 += __shfl_xor(a1, 32);
    a2 += __shfl_xor(a2, 32); a3 += __shfl_xor(a3, 32);

    if (half == 0) {
        float4 bv = ((const float4*)bias)[l];
        float g0 = eluf(a0 * dih + bv.x);
        float g1 = eluf(a1 * dih + bv.y);
        float g2 = eluf(a2 * dih + bv.z);
        float g3 = eluf(a3 * dih + bv.w);
        const float ac = alphas[aidx];
        float4 s2 = make_float4(0.f, 0.f, 0.f, 0.f);
        if (!sl_zero) s2 = ((const float4*)sl)[(size_t)n * 32 + l];
        float hx0 = 0.f, hx1 = 0.f, hx2 = 0.f, hx3 = 0.f;
        if (ac != 0.f) {
            float4 hv = ((const float4*)h0)[(size_t)n * 32 + l];
            hx0 = hv.x; hx1 = hv.y; hx2 = hv.z; hx3 = hv.w;
        }
        float o0 = 2.f * g0 - s2.x + ac * hx0;
        float o1 = 2.f * g1 - s2.y + ac * hx1;
        float o2 = 2.f * g2 - s2.z + ac * hx2;
        float o3 = 2.f * g3 - s2.w + ac * hx3;
        ((float4*)hnew)[(size_t)n * 32 + l] = make_float4(o0, o1, o2, o3);
        uint2 pb; pb.x = pack2(o0, o1); pb.y = pack2(o2, o3);
        ((uint2*)hnewb)[(size_t)n * 32 + l] = pb;
    }
}

// ---------- final: [NN,128] @ [128,40] + bias, log_softmax ----------
__global__ __launch_bounds__(64) void k_out(const float* __restrict__ t,
                                            const float* __restrict__ w,
                                            const float* __restrict__ b,
                                            float* __restrict__ out) {
    const int n = blockIdx.x;
    const int lane = threadIdx.x;
    float acc = 0.f;
    if (lane < OUT_C) {
        for (int k = 0; k < HID; ++k) acc += t[(size_t)n * HID + k] * w[k * OUT_C + lane];
        acc += b[lane];
    }
    float v = (lane < OUT_C) ? acc : -INFINITY;
    for (int off = 32; off; off >>= 1) v = fmaxf(v, __shfl_down(v, off));
    float mx = __shfl(v, 0);
    float ex = (lane < OUT_C) ? __expf(acc - mx) : 0.f;
    float sv = ex;
    for (int off = 32; off; off >>= 1) sv += __shfl_down(sv, off);
    float lse = logf(__shfl(sv, 0));
    if (lane < OUT_C) out[(size_t)n * OUT_C + lane] = acc - mx - lse;
}

// ---------- host ----------
extern "C" void kernel_launch(void* const* d_in, const int* in_sizes, int n_in,
                              void* d_out, int out_size, void* d_ws, size_t ws_size,
                              hipStream_t stream) {
    const float* x      = (const float*)d_in[0];
    const int*   ei     = (const int*)  d_in[1];
    const float* fc0w   = (const float*)d_in[2];
    const float* fc0b   = (const float*)d_in[3];
    const float* linw   = (const float*)d_in[4];
    const float* attS   = (const float*)d_in[5];
    const float* attD   = (const float*)d_in[6];
    const float* cbias  = (const float*)d_in[7];
    const float* alphas = (const float*)d_in[8];
    const float* fc1w   = (const float*)d_in[9];
    const float* fc1b   = (const float*)d_in[10];
    float* out = (float*)d_out;

    char* p = (char*)d_ws;
    auto alloc = [&](size_t bytes) { void* q = (void*)p; p += (bytes + 255) / 256 * 256; return q; };
    const size_t NNH = (size_t)NN * HID * 4;
    float* h0 = (float*)alloc(NNH);
    float* bA = (float*)alloc(NNH);
    float* bB = (float*)alloc(NNH);
    float* bC = (float*)alloc(NNH);
    unsigned short* lastb = (unsigned short*)alloc((size_t)NN * HID * 2);
    unsigned short* hpb   = (unsigned short*)alloc((size_t)NN * HID * 2);
    float* aSb = (float*)alloc((size_t)NN * NHEAD * 4);
    float* aDb = (float*)alloc((size_t)NN * NHEAD * 4);
    unsigned short* WT0 = (unsigned short*)alloc((size_t)HID * IN_C * 2);
    unsigned short* WTL = (unsigned short*)alloc((size_t)4 * HID * HID * 2);
    int* deg      = (int*)alloc((size_t)(NN + 1) * 4);
    int* rowstart = (int*)alloc((size_t)(NN + 1) * 4);
    int* part     = (int*)alloc(64 * 4);
    int* csr      = (int*)alloc((size_t)E_CNT * 4);
    int* cursor   = deg;   // safe: k_scanblk reads deg[i] before writing cursor[i]; deg dead after

    const int* esrc = ei;
    const int* edst = ei + E_CNT;
    const int NB = (NN + 1023) / 1024;

    // CSR build
    hipMemsetAsync(deg, 0, (size_t)NN * 4, stream);
    k_hist<<<(E_CNT + 255) / 256, 256, 0, stream>>>(edst, deg);
    k_part<<<NB, 1024, 0, stream>>>(deg, part);
    k_scanpart<<<1, 64, 0, stream>>>(part, rowstart, NB);
    k_scanblk<<<NB, 1024, 0, stream>>>(deg, part, rowstart, cursor);
    k_scatter<<<(E_CNT + 255) / 256, 256, 0, stream>>>(esrc, edst, cursor, csr);

    // weights -> transposed bf16 (fc0 + 4 lin layers)
    {
        dim3 g0(IN_C / 32, HID / 32, 1);
        k_wt<<<g0, 256, 0, stream>>>(fc0w, WT0, IN_C);
        dim3 gl(HID / 32, HID / 32, 4);
        k_wt<<<gl, 256, 0, stream>>>(linw + (size_t)HID * HID, WTL, HID);
    }

    const int GB = (NN + 127) / 128;   // 391
    // fused: h0 = x@fc0w + fc0b ; bA = 2*elu(cbias0) + a4*h0 ; lastb = bf16(bA)
    k_mgemm<IN_C, 1, 2><<<GB, 256, 0, stream>>>(x, WT0, fc0b, cbias, alphas, h0, bA, lastb);

    float* last = bA; float* sl = bB; float* nxt = bC;
    for (int i = 1; i < NLAYER; ++i) {
        k_mgemm<HID, 0, 0><<<GB, 256, 0, stream>>>(lastb, WTL + (size_t)(i - 1) * HID * HID,
                                                   nullptr, nullptr, nullptr, nullptr, nullptr, hpb);
        k_att<<<(NN * NHEAD + 255) / 256, 256, 0, stream>>>(hpb, attS + i * NHEAD * CPH, attD + i * NHEAD * CPH, aSb, aDb);
        k_agg<<<NN / 4, 256, 0, stream>>>(hpb, aSb, aDb, rowstart, csr,
                                          cbias + i * HID, h0, sl, alphas, NLAYER - 1 - i, (i == 1) ? 1 : 0,
                                          nxt, (unsigned int*)lastb);
        float* tmp = sl; sl = last; last = nxt; nxt = tmp;
    }

    k_out<<<NN, 64, 0, stream>>>(last, fc1w, fc1b, out);
}